// Round 1
// baseline (384.107 us; speedup 1.0000x reference)
//
#include <hip/hip_runtime.h>
#include <hip/hip_fp16.h>
#include <math.h>

// ---------------------------------------------------------------------------
// 3-layer GCN. R2: bucketed CSR build. R3: fp16 gathers. R4: LDS-only CSR.
// R5: MFMA dense transforms, fp16 buffers. R6: pre-scaled g. R7: oct-per-row
// aggs. R8: unroll-4 gathers, fused prep. R9: layer-2 agg split into two
// half-feature passes (12.8 MB working set for L2 hit rate).
// R10: 8-deep gather pipeline in all agg kernels (2x lines in flight per
//      oct) + non-temporal hints on all pure streams (col reads, agg/gemm
//      outputs, gemm X loads, prep x loads, CSR-build edge streams) so L2
//      retains the randomly-gathered feature tables. Theory: agg kernels are
//      latency/hit-rate bound, not request-count bound.
// ---------------------------------------------------------------------------

#define THREADS 256
#define SCANT 512
#define BSHIFT 8               // nodes per bucket = 256
#define BNODES (1 << BSHIFT)
#define NBUCK_MAX 512
#define EPT 16
#define CHUNK (THREADS * EPT)

typedef _Float16 half8 __attribute__((ext_vector_type(8)));
typedef float floatx4 __attribute__((ext_vector_type(4)));
typedef unsigned int uintx4 __attribute__((ext_vector_type(4)));
typedef int intx4 __attribute__((ext_vector_type(4)));

__device__ __forceinline__ float celu1(float v) {
    return v > 0.0f ? v : expm1f(v);
}

__device__ __forceinline__ void add8(float* acc, uint4 u) {
    const __half2* h2 = (const __half2*)&u;
    float2 f;
    f = __half22float2(h2[0]); acc[0] += f.x; acc[1] += f.y;
    f = __half22float2(h2[1]); acc[2] += f.x; acc[3] += f.y;
    f = __half22float2(h2[2]); acc[4] += f.x; acc[5] += f.y;
    f = __half22float2(h2[3]); acc[6] += f.x; acc[7] += f.y;
}

// non-temporal 16B store of 4x half2
__device__ __forceinline__ void stnt16(void* p, const __half2* hp) {
    const unsigned int* u = (const unsigned int*)hp;
    uintx4 v; v.x = u[0]; v.y = u[1]; v.z = u[2]; v.w = u[3];
    __builtin_nontemporal_store(v, (uintx4*)p);
}

// ---- fused prep: xg = dinv*x (fp16) ; Wt = W^T (fp16) ---------------------

__global__ __launch_bounds__(THREADS) void prep_kernel(
    const float* __restrict__ x, const float* __restrict__ dinv,
    __half* __restrict__ xg,
    const float* __restrict__ W1, __half* __restrict__ Wt1,
    const float* __restrict__ W2, __half* __restrict__ Wt2,
    const float* __restrict__ W3, __half* __restrict__ Wt3, int n8) {
    const int nf2h = (n8 + THREADS - 1) / THREADS;  // blocks for f2h part
    int b = blockIdx.x;
    if (b < nf2h) {
        int i = b * THREADS + threadIdx.x;
        if (i < n8) {
            float d = dinv[i >> 3];
            const floatx4* x4 = (const floatx4*)x;
            floatx4 a = __builtin_nontemporal_load(x4 + i * 2);
            floatx4 c = __builtin_nontemporal_load(x4 + i * 2 + 1);
            __half2 h[4] = {__floats2half2_rn(a.x * d, a.y * d), __floats2half2_rn(a.z * d, a.w * d),
                            __floats2half2_rn(c.x * d, c.y * d), __floats2half2_rn(c.z * d, c.w * d)};
            ((uint4*)xg)[i] = *(uint4*)h;
        }
        return;
    }
    b -= nf2h;
    const float* W; __half* Wt; int K, F;
    if (b < 32)      { W = W1; Wt = Wt1; K = 64;  F = 128; }
    else if (b < 96) { W = W2; Wt = Wt2; K = 128; F = 128; b -= 32; }
    else             { W = W3; Wt = Wt3; K = 128; F = 64;  b -= 96; }
    int i = b * THREADS + threadIdx.x;
    if (i < K * F) {
        int k = i / F, f = i % F;
        Wt[f * K + k] = __float2half(W[i]);
    }
}

// ---- CSR build: bucketed counting sort, LDS-atomic only -------------------

__global__ __launch_bounds__(THREADS) void bucket_hist_kernel(
    const int* __restrict__ dst, int* __restrict__ bucketCnt, int E, int NBUCK) {
    __shared__ int lcnt[NBUCK_MAX];
    for (int i = threadIdx.x; i < NBUCK; i += THREADS) lcnt[i] = 0;
    __syncthreads();
    const int E4 = E >> 2;
    for (int e4 = blockIdx.x * THREADS + threadIdx.x; e4 < E4; e4 += gridDim.x * THREADS) {
        intx4 d = __builtin_nontemporal_load((const intx4*)dst + e4);
        atomicAdd(&lcnt[d.x >> BSHIFT], 1);
        atomicAdd(&lcnt[d.y >> BSHIFT], 1);
        atomicAdd(&lcnt[d.z >> BSHIFT], 1);
        atomicAdd(&lcnt[d.w >> BSHIFT], 1);
    }
    if (blockIdx.x == 0) {
        for (int e = (E4 << 2) + threadIdx.x; e < E; e += THREADS)
            atomicAdd(&lcnt[dst[e] >> BSHIFT], 1);
    }
    __syncthreads();
    for (int i = threadIdx.x; i < NBUCK; i += THREADS)
        if (lcnt[i]) atomicAdd(&bucketCnt[i], lcnt[i]);
}

__global__ __launch_bounds__(SCANT) void bucket_scan_kernel(
    const int* __restrict__ bucketCnt, int* __restrict__ bucketOff,
    int* __restrict__ bucketCur, int* __restrict__ rowptr, int NBUCK, int N) {
    __shared__ int s[SCANT];
    const int tid = threadIdx.x;
    int v = (tid < NBUCK) ? bucketCnt[tid] : 0;
    s[tid] = v;
    __syncthreads();
    for (int off = 1; off < SCANT; off <<= 1) {
        int t = 0;
        if (tid >= off) t = s[tid - off];
        __syncthreads();
        if (tid >= off) s[tid] += t;
        __syncthreads();
    }
    if (tid < NBUCK) {
        int ex = s[tid] - v;
        bucketOff[tid] = ex;
        bucketCur[tid] = ex;
    }
    if (tid == 0) {
        int total = s[SCANT - 1];
        bucketOff[NBUCK] = total;  // == E
        rowptr[N] = total;
    }
}

// packed edge record: (dst & (BNODES-1)) << 20 | src   (valid: N < 2^20)
__global__ __launch_bounds__(THREADS) void bucket_scatter_kernel(
    const int* __restrict__ src, const int* __restrict__ dst,
    int* __restrict__ bucketCur, int* __restrict__ ePack, int E, int NBUCK) {
    __shared__ int lcnt[NBUCK_MAX];
    __shared__ int lbase[NBUCK_MAX];
    for (int i = threadIdx.x; i < NBUCK; i += THREADS) lcnt[i] = 0;
    __syncthreads();
    const int base = blockIdx.x * CHUNK;
    int bk[EPT], rk[EPT], pk[EPT];
#pragma unroll
    for (int i = 0; i < EPT; ++i) {
        int e = base + i * THREADS + threadIdx.x;
        if (e < E) {
            int d = __builtin_nontemporal_load(dst + e);
            int s = __builtin_nontemporal_load(src + e);
            pk[i] = ((d & (BNODES - 1)) << 20) | s;
            bk[i] = d >> BSHIFT;
            rk[i] = atomicAdd(&lcnt[bk[i]], 1);
        } else {
            bk[i] = -1;
        }
    }
    __syncthreads();
    for (int i = threadIdx.x; i < NBUCK; i += THREADS)
        if (lcnt[i]) lbase[i] = atomicAdd(&bucketCur[i], lcnt[i]);
    __syncthreads();
#pragma unroll
    for (int i = 0; i < EPT; ++i) {
        if (bk[i] >= 0) ePack[lbase[bk[i]] + rk[i]] = pk[i];
    }
}

// one block per bucket: LDS hist -> LDS scan -> rowptr/dinv/col
__global__ __launch_bounds__(THREADS) void build_kernel(
    const int* __restrict__ ePack, const int* __restrict__ bucketOff,
    int* __restrict__ rowptr, float* __restrict__ dinv,
    int* __restrict__ col, int N) {
    __shared__ int hist[BNODES];
    __shared__ int scn[BNODES];
    const int tid = threadIdx.x;
    const int b = blockIdx.x;
    const int off = bucketOff[b];
    const int end = bucketOff[b + 1];
    hist[tid] = 0;
    __syncthreads();
    for (int e = off + tid; e < end; e += THREADS)
        atomicAdd(&hist[((unsigned)ePack[e]) >> 20], 1);
    __syncthreads();
    int deg = hist[tid];
    scn[tid] = deg;
    __syncthreads();
    for (int o = 1; o < BNODES; o <<= 1) {
        int t = 0;
        if (tid >= o) t = scn[tid - o];
        __syncthreads();
        if (tid >= o) scn[tid] += t;
        __syncthreads();
    }
    int ex = off + scn[tid] - deg;
    const int node = (b << BSHIFT) + tid;
    if (node < N) {
        rowptr[node] = ex;
        dinv[node] = rsqrtf((float)deg + 1.0f);  // +1 self-loop
    }
    scn[tid] = ex;
    __syncthreads();
    for (int e = off + tid; e < end; e += THREADS) {
        int p = ePack[e];
        int pos = atomicAdd(&scn[((unsigned)p) >> 20], 1);
        __builtin_nontemporal_store(p & 0xFFFFF, col + pos);
    }
}

// ---- Aggregation F=64: one oct (8 lanes) per row, 8 edges in flight -------

template <bool ACT, bool OUTH>
__global__ __launch_bounds__(THREADS) void agg64g_kernel(
    const __half* __restrict__ g, const int* __restrict__ rowptr,
    const int* __restrict__ col, const float* __restrict__ dinv,
    const float* __restrict__ bias, void* __restrict__ outv, int N) {
    const int tid = threadIdx.x;
    const int lane = tid & 63, wave = tid >> 6;
    const int oct = lane >> 3, sub = lane & 7;
    const int r = blockIdx.x * 32 + wave * 8 + oct;
    const uint4* __restrict__ g4 = (const uint4*)g + sub;  // 8 uint4 per row
    const bool valid = (r < N);
    int start = 0, end = 0;
    if (valid) { start = rowptr[r]; end = rowptr[r + 1]; }

    float acc[8] = {0.f, 0.f, 0.f, 0.f, 0.f, 0.f, 0.f, 0.f};
    if (valid) add8(acc, g4[(size_t)r * 8]);  // self-loop

    int e = start;
    for (; e + 8 <= end; e += 8) {
        int c[8];
#pragma unroll
        for (int i = 0; i < 8; ++i) c[i] = __builtin_nontemporal_load(col + e + i);
        uint4 u[8];
#pragma unroll
        for (int i = 0; i < 8; ++i) u[i] = g4[(size_t)c[i] * 8];
#pragma unroll
        for (int i = 0; i < 8; ++i) add8(acc, u[i]);
    }
    for (; e + 2 <= end; e += 2) {
        int c0 = __builtin_nontemporal_load(col + e);
        int c1 = __builtin_nontemporal_load(col + e + 1);
        uint4 u0 = g4[(size_t)c0 * 8];
        uint4 u1 = g4[(size_t)c1 * 8];
        add8(acc, u0); add8(acc, u1);
    }
    if (e < end) add8(acc, g4[(size_t)__builtin_nontemporal_load(col + e) * 8]);

    if (valid) {
        const float dr = dinv[r];
        float res[8];
#pragma unroll
        for (int k = 0; k < 8; ++k) res[k] = acc[k] * dr;
        if constexpr (ACT) {
            const float* bp = bias + sub * 8;
#pragma unroll
            for (int k = 0; k < 8; ++k) res[k] = celu1(res[k] + bp[k]);
        }
        if constexpr (OUTH) {
            __half2 hp[4] = {__floats2half2_rn(res[0], res[1]), __floats2half2_rn(res[2], res[3]),
                             __floats2half2_rn(res[4], res[5]), __floats2half2_rn(res[6], res[7])};
            stnt16((__half*)outv + (size_t)r * 64 + sub * 8, hp);
        } else {
            float* o = (float*)outv + (size_t)r * 64 + sub * 8;
            floatx4 o0 = {res[0], res[1], res[2], res[3]};
            floatx4 o1 = {res[4], res[5], res[6], res[7]};
            __builtin_nontemporal_store(o0, (floatx4*)o);
            __builtin_nontemporal_store(o1, (floatx4*)o + 1);
        }
    }
}

// ---- Aggregation F=128, two half-feature passes, 8 edges in flight --------
// 8-lane oct per (row, half): pass working set 12.8 MB (vs 25.6) for L2.
// blockIdx >= NB selects the upper feature half.

__global__ __launch_bounds__(THREADS) void agg128g_kernel(
    const __half* __restrict__ g, const int* __restrict__ rowptr,
    const int* __restrict__ col, const float* __restrict__ dinv,
    __half* __restrict__ out, int N, int NB) {
    const int tid = threadIdx.x;
    const int lane = tid & 63, wave = tid >> 6;
    const int oct = lane >> 3, sub = lane & 7;
    int bx = blockIdx.x;
    int half = 0;
    if (bx >= NB) { half = 1; bx -= NB; }
    const int r = bx * 32 + wave * 8 + oct;
    // pre-offset by feature half + sub; row stride = 16 uint4 (128 halves)
    const uint4* __restrict__ g4 = (const uint4*)g + half * 8 + sub;
    const bool valid = (r < N);
    int start = 0, end = 0;
    if (valid) { start = rowptr[r]; end = rowptr[r + 1]; }

    float acc[8] = {0.f, 0.f, 0.f, 0.f, 0.f, 0.f, 0.f, 0.f};
    if (valid) add8(acc, g4[(size_t)r * 16]);  // self-loop

    int e = start;
    for (; e + 8 <= end; e += 8) {
        int c[8];
#pragma unroll
        for (int i = 0; i < 8; ++i) c[i] = __builtin_nontemporal_load(col + e + i);
        uint4 u[8];
#pragma unroll
        for (int i = 0; i < 8; ++i) u[i] = g4[(size_t)c[i] * 16];
#pragma unroll
        for (int i = 0; i < 8; ++i) add8(acc, u[i]);
    }
    for (; e + 2 <= end; e += 2) {
        int c0 = __builtin_nontemporal_load(col + e);
        int c1 = __builtin_nontemporal_load(col + e + 1);
        uint4 u0 = g4[(size_t)c0 * 16];
        uint4 u1 = g4[(size_t)c1 * 16];
        add8(acc, u0); add8(acc, u1);
    }
    if (e < end) add8(acc, g4[(size_t)__builtin_nontemporal_load(col + e) * 16]);

    if (valid) {
        const float dr = dinv[r];
        __half2 hp[4] = {__floats2half2_rn(acc[0] * dr, acc[1] * dr),
                         __floats2half2_rn(acc[2] * dr, acc[3] * dr),
                         __floats2half2_rn(acc[4] * dr, acc[5] * dr),
                         __floats2half2_rn(acc[6] * dr, acc[7] * dr)};
        stnt16(out + (size_t)r * 128 + half * 64 + sub * 8, hp);
    }
}

// ---- MFMA dense transform: out[N,F] = [dinv*] act(X @ W + b) --------------

template <int K, int F, bool ACT, bool SCALE>
__global__ __launch_bounds__(THREADS) void mfma_gemm_kernel(
    const __half* __restrict__ X, const __half* __restrict__ Wt,
    const float* __restrict__ bias, const float* __restrict__ dinv,
    __half* __restrict__ outh, int N) {
    constexpr int KP = K + 8;  // padded LDS row stride (halves)
    constexpr int NT = F / 16;
    __shared__ __half Ws[F * KP];

    const int tid = threadIdx.x;
    for (int i = tid; i < F * K / 8; i += THREADS) {
        int f = i / (K / 8), kg = i % (K / 8);
        *(uint4*)&Ws[f * KP + kg * 8] = ((const uint4*)Wt)[i];
    }
    __syncthreads();

    const int wave = tid >> 6, lane = tid & 63;
    const int q = lane >> 4, mn = lane & 15;
    const int row0w = blockIdx.x * 64 + wave * 16;
    int arow = row0w + mn;
    if (arow >= N) arow = N - 1;  // clamp loads; garbage rows masked on store

    floatx4 acc[NT];
#pragma unroll
    for (int t = 0; t < NT; ++t) acc[t] = {0.f, 0.f, 0.f, 0.f};

    const __half* xp = X + (size_t)arow * K + q * 8;
#pragma unroll
    for (int k0 = 0; k0 < K; k0 += 32) {
        half8 a = __builtin_nontemporal_load((const half8*)(xp + k0));
#pragma unroll
        for (int t = 0; t < NT; ++t) {
            half8 b = *(const half8*)&Ws[(t * 16 + mn) * KP + k0 + q * 8];
            acc[t] = __builtin_amdgcn_mfma_f32_16x16x32_f16(a, b, acc[t], 0, 0, 0);
        }
    }

    // D: reg i <-> row = row0w + q*4 + i, col = t*16 + mn
    const int orow0 = row0w + q * 4;
    float dv[4] = {1.f, 1.f, 1.f, 1.f};
    if constexpr (SCALE) {
#pragma unroll
        for (int i = 0; i < 4; ++i) {
            int r = orow0 + i;
            if (r < N) dv[i] = dinv[r];
        }
    }
#pragma unroll
    for (int t = 0; t < NT; ++t) {
        const int coln = t * 16 + mn;
        float bv = 0.f;
        if constexpr (ACT) bv = bias[coln];
#pragma unroll
        for (int i = 0; i < 4; ++i) {
            int r = orow0 + i;
            if (r < N) {
                float v = acc[t][i];
                if constexpr (ACT) v = celu1(v + bv);
                if constexpr (SCALE) v *= dv[i];
                __builtin_nontemporal_store((_Float16)v, (_Float16*)outh + (size_t)r * F + coln);
            }
        }
    }
}

// ---------------------------------------------------------------------------

extern "C" void kernel_launch(void* const* d_in, const int* in_sizes, int n_in,
                              void* d_out, int out_size, void* d_ws, size_t ws_size,
                              hipStream_t stream) {
    const float* x  = (const float*)d_in[0];
    const int*   ei = (const int*)d_in[1];
    const float* W1 = (const float*)d_in[2];
    const float* b1 = (const float*)d_in[3];
    const float* W2 = (const float*)d_in[4];
    const float* b2 = (const float*)d_in[5];
    const float* W3 = (const float*)d_in[6];
    const float* b3 = (const float*)d_in[7];
    float* out = (float*)d_out;

    const int N = in_sizes[0] / 64;   // 100000
    const int E = in_sizes[1] / 2;    // 1600000
    const int* src = ei;
    const int* dst = ei + E;
    const int NBUCK = (N + BNODES - 1) >> BSHIFT;  // 391

    char* p = (char*)d_ws;
    auto carve = [&](size_t bytes) {
        void* q = p;
        p += (bytes + 255) & ~(size_t)255;
        return q;
    };
    int*    rowptr    = (int*)carve((size_t)(N + 1) * sizeof(int));
    int*    col       = (int*)carve((size_t)E * sizeof(int));
    float*  dinv      = (float*)carve((size_t)N * sizeof(float));
    int*    bucketCnt = (int*)carve(NBUCK_MAX * sizeof(int));
    int*    bucketOff = (int*)carve((NBUCK_MAX + 1) * sizeof(int));
    int*    bucketCur = (int*)carve(NBUCK_MAX * sizeof(int));
    __half* xg        = (__half*)carve((size_t)N * 64 * sizeof(__half));
    __half* Wt1       = (__half*)carve(64 * 128 * sizeof(__half));
    __half* Wt2       = (__half*)carve(128 * 128 * sizeof(__half));
    __half* Wt3       = (__half*)carve(128 * 64 * sizeof(__half));
    __half* FA        = (__half*)carve((size_t)N * 128 * sizeof(__half));
    __half* FB        = (__half*)carve((size_t)N * 128 * sizeof(__half));
    int*    ePack     = (int*)FB;  // 6.4MB; consumed by build_kernel before gemm1 writes FB

    const int AB64  = (N + 31) / 32;
    const int AB128 = (N + 31) / 32;  // 32 rows/block per half-pass
    const int GBM = (N + 63) / 64;
    const int SB = (E + CHUNK - 1) / CHUNK;
    const int n8 = N * 8;
    const int PB = (n8 + THREADS - 1) / THREADS + 128;  // f2h blocks + 128 w2h blocks

    // --- CSR build, then fused precision prep (needs dinv) ---
    hipMemsetAsync(bucketCnt, 0, NBUCK_MAX * sizeof(int), stream);
    bucket_hist_kernel<<<256, THREADS, 0, stream>>>(dst, bucketCnt, E, NBUCK);
    bucket_scan_kernel<<<1, SCANT, 0, stream>>>(bucketCnt, bucketOff, bucketCur, rowptr, NBUCK, N);
    bucket_scatter_kernel<<<SB, THREADS, 0, stream>>>(src, dst, bucketCur, ePack, E, NBUCK);
    build_kernel<<<NBUCK, THREADS, 0, stream>>>(ePack, bucketOff, rowptr, dinv, col, N);
    prep_kernel<<<PB, THREADS, 0, stream>>>(x, dinv, xg, W1, Wt1, W2, Wt2, W3, Wt3, n8);

    // --- Layer 1: s1 = Agg(x);  g1 = dinv*celu(s1@W1+b1)  (pre-scaled) ---
    agg64g_kernel<false, true><<<AB64, THREADS, 0, stream>>>(xg, rowptr, col, dinv, nullptr, FA, N);
    mfma_gemm_kernel<64, 128, true, true><<<GBM, THREADS, 0, stream>>>(FA, Wt1, b1, dinv, FB, N);

    // --- Layer 2: s2 = Agg(g1) (two half-feature passes);  a2 = celu(s2@W2+b2) ---
    agg128g_kernel<<<2 * AB128, THREADS, 0, stream>>>(FB, rowptr, col, dinv, FA, N, AB128);
    mfma_gemm_kernel<128, 128, true, false><<<GBM, THREADS, 0, stream>>>(FA, Wt2, b2, dinv, FB, N);

    // --- Layer 3: g3 = dinv*(a2@W3); out = celu(dinv*(g3[r]+sum g3)+b3) ---
    mfma_gemm_kernel<128, 64, false, true><<<GBM, THREADS, 0, stream>>>(FB, Wt3, nullptr, dinv, FA, N);
    agg64g_kernel<true, false><<<AB64, THREADS, 0, stream>>>(FA, rowptr, col, dinv, b3, out, N);
}

// Round 2
// 317.452 us; speedup vs baseline: 1.2100x; 1.2100x over previous
//
#include <hip/hip_runtime.h>
#include <hip/hip_fp16.h>
#include <math.h>

// ---------------------------------------------------------------------------
// 3-layer GCN. R2: bucketed CSR build. R3: fp16 gathers. R4: LDS-only CSR.
// R5: MFMA dense transforms, fp16 buffers. R6: pre-scaled g. R7: oct-per-row
// aggs. R8: unroll-4 gathers, fused prep. R9: layer-2 agg split into two
// half-feature passes (12.8 MB working set for L2 hit rate).
// R10 (REVERTED): 8-deep pipeline + broad nt hints — occupancy 70->45%,
//      FETCH +8MB, agg128 58.5->66us. NT on producer/consumer streams evicts
//      exactly what the next kernel gathers; extra depth only cost VGPRs.
// R11: back to R9 structure + LDS col staging in the agg kernels: one
//      coalesced col load per edge per block, then LDS broadcast per oct
//      (was 8-replica scalar global loads). rowptr staged too. nt retained
//      ONLY on provably-dead streams (prep x loads, final out stores).
// ---------------------------------------------------------------------------

#define THREADS 256
#define SCANT 512
#define BSHIFT 8               // nodes per bucket = 256
#define BNODES (1 << BSHIFT)
#define NBUCK_MAX 512
#define EPT 16
#define CHUNK (THREADS * EPT)
#define COLCAP 4096            // LDS col slice per block (avg block = 512 edges)

typedef _Float16 half8 __attribute__((ext_vector_type(8)));
typedef float floatx4 __attribute__((ext_vector_type(4)));

__device__ __forceinline__ float celu1(float v) {
    return v > 0.0f ? v : expm1f(v);
}

__device__ __forceinline__ void add8(float* acc, uint4 u) {
    const __half2* h2 = (const __half2*)&u;
    float2 f;
    f = __half22float2(h2[0]); acc[0] += f.x; acc[1] += f.y;
    f = __half22float2(h2[1]); acc[2] += f.x; acc[3] += f.y;
    f = __half22float2(h2[2]); acc[4] += f.x; acc[5] += f.y;
    f = __half22float2(h2[3]); acc[6] += f.x; acc[7] += f.y;
}

// ---- fused prep: xg = dinv*x (fp16) ; Wt = W^T (fp16) ---------------------

__global__ __launch_bounds__(THREADS) void prep_kernel(
    const float* __restrict__ x, const float* __restrict__ dinv,
    __half* __restrict__ xg,
    const float* __restrict__ W1, __half* __restrict__ Wt1,
    const float* __restrict__ W2, __half* __restrict__ Wt2,
    const float* __restrict__ W3, __half* __restrict__ Wt3, int n8) {
    const int nf2h = (n8 + THREADS - 1) / THREADS;  // blocks for f2h part
    int b = blockIdx.x;
    if (b < nf2h) {
        int i = b * THREADS + threadIdx.x;
        if (i < n8) {
            float d = dinv[i >> 3];
            const floatx4* x4 = (const floatx4*)x;
            floatx4 a = __builtin_nontemporal_load(x4 + i * 2);   // x never re-read
            floatx4 c = __builtin_nontemporal_load(x4 + i * 2 + 1);
            __half2 h[4] = {__floats2half2_rn(a.x * d, a.y * d), __floats2half2_rn(a.z * d, a.w * d),
                            __floats2half2_rn(c.x * d, c.y * d), __floats2half2_rn(c.z * d, c.w * d)};
            ((uint4*)xg)[i] = *(uint4*)h;
        }
        return;
    }
    b -= nf2h;
    const float* W; __half* Wt; int K, F;
    if (b < 32)      { W = W1; Wt = Wt1; K = 64;  F = 128; }
    else if (b < 96) { W = W2; Wt = Wt2; K = 128; F = 128; b -= 32; }
    else             { W = W3; Wt = Wt3; K = 128; F = 64;  b -= 96; }
    int i = b * THREADS + threadIdx.x;
    if (i < K * F) {
        int k = i / F, f = i % F;
        Wt[f * K + k] = __float2half(W[i]);
    }
}

// ---- CSR build: bucketed counting sort, LDS-atomic only -------------------

__global__ __launch_bounds__(THREADS) void bucket_hist_kernel(
    const int* __restrict__ dst, int* __restrict__ bucketCnt, int E, int NBUCK) {
    __shared__ int lcnt[NBUCK_MAX];
    for (int i = threadIdx.x; i < NBUCK; i += THREADS) lcnt[i] = 0;
    __syncthreads();
    const int E4 = E >> 2;
    for (int e4 = blockIdx.x * THREADS + threadIdx.x; e4 < E4; e4 += gridDim.x * THREADS) {
        int4 d = ((const int4*)dst)[e4];
        atomicAdd(&lcnt[d.x >> BSHIFT], 1);
        atomicAdd(&lcnt[d.y >> BSHIFT], 1);
        atomicAdd(&lcnt[d.z >> BSHIFT], 1);
        atomicAdd(&lcnt[d.w >> BSHIFT], 1);
    }
    if (blockIdx.x == 0) {
        for (int e = (E4 << 2) + threadIdx.x; e < E; e += THREADS)
            atomicAdd(&lcnt[dst[e] >> BSHIFT], 1);
    }
    __syncthreads();
    for (int i = threadIdx.x; i < NBUCK; i += THREADS)
        if (lcnt[i]) atomicAdd(&bucketCnt[i], lcnt[i]);
}

__global__ __launch_bounds__(SCANT) void bucket_scan_kernel(
    const int* __restrict__ bucketCnt, int* __restrict__ bucketOff,
    int* __restrict__ bucketCur, int* __restrict__ rowptr, int NBUCK, int N) {
    __shared__ int s[SCANT];
    const int tid = threadIdx.x;
    int v = (tid < NBUCK) ? bucketCnt[tid] : 0;
    s[tid] = v;
    __syncthreads();
    for (int off = 1; off < SCANT; off <<= 1) {
        int t = 0;
        if (tid >= off) t = s[tid - off];
        __syncthreads();
        if (tid >= off) s[tid] += t;
        __syncthreads();
    }
    if (tid < NBUCK) {
        int ex = s[tid] - v;
        bucketOff[tid] = ex;
        bucketCur[tid] = ex;
    }
    if (tid == 0) {
        int total = s[SCANT - 1];
        bucketOff[NBUCK] = total;  // == E
        rowptr[N] = total;
    }
}

// packed edge record: (dst & (BNODES-1)) << 20 | src   (valid: N < 2^20)
__global__ __launch_bounds__(THREADS) void bucket_scatter_kernel(
    const int* __restrict__ src, const int* __restrict__ dst,
    int* __restrict__ bucketCur, int* __restrict__ ePack, int E, int NBUCK) {
    __shared__ int lcnt[NBUCK_MAX];
    __shared__ int lbase[NBUCK_MAX];
    for (int i = threadIdx.x; i < NBUCK; i += THREADS) lcnt[i] = 0;
    __syncthreads();
    const int base = blockIdx.x * CHUNK;
    int bk[EPT], rk[EPT], pk[EPT];
#pragma unroll
    for (int i = 0; i < EPT; ++i) {
        int e = base + i * THREADS + threadIdx.x;
        if (e < E) {
            int d = dst[e];
            pk[i] = ((d & (BNODES - 1)) << 20) | src[e];
            bk[i] = d >> BSHIFT;
            rk[i] = atomicAdd(&lcnt[bk[i]], 1);
        } else {
            bk[i] = -1;
        }
    }
    __syncthreads();
    for (int i = threadIdx.x; i < NBUCK; i += THREADS)
        if (lcnt[i]) lbase[i] = atomicAdd(&bucketCur[i], lcnt[i]);
    __syncthreads();
#pragma unroll
    for (int i = 0; i < EPT; ++i) {
        if (bk[i] >= 0) ePack[lbase[bk[i]] + rk[i]] = pk[i];
    }
}

// one block per bucket: LDS hist -> LDS scan -> rowptr/dinv/col
__global__ __launch_bounds__(THREADS) void build_kernel(
    const int* __restrict__ ePack, const int* __restrict__ bucketOff,
    int* __restrict__ rowptr, float* __restrict__ dinv,
    int* __restrict__ col, int N) {
    __shared__ int hist[BNODES];
    __shared__ int scn[BNODES];
    const int tid = threadIdx.x;
    const int b = blockIdx.x;
    const int off = bucketOff[b];
    const int end = bucketOff[b + 1];
    hist[tid] = 0;
    __syncthreads();
    for (int e = off + tid; e < end; e += THREADS)
        atomicAdd(&hist[((unsigned)ePack[e]) >> 20], 1);
    __syncthreads();
    int deg = hist[tid];
    scn[tid] = deg;
    __syncthreads();
    for (int o = 1; o < BNODES; o <<= 1) {
        int t = 0;
        if (tid >= o) t = scn[tid - o];
        __syncthreads();
        if (tid >= o) scn[tid] += t;
        __syncthreads();
    }
    int ex = off + scn[tid] - deg;
    const int node = (b << BSHIFT) + tid;
    if (node < N) {
        rowptr[node] = ex;
        dinv[node] = rsqrtf((float)deg + 1.0f);  // +1 self-loop
    }
    scn[tid] = ex;
    __syncthreads();
    for (int e = off + tid; e < end; e += THREADS) {
        int p = ePack[e];
        int pos = atomicAdd(&scn[((unsigned)p) >> 20], 1);
        col[pos] = p & 0xFFFFF;   // plain store: col re-read by aggs soon
    }
}

// ---- Aggregation F=64: oct (8 lanes) per row, LDS-staged col --------------

template <bool ACT, bool OUTH>
__global__ __launch_bounds__(THREADS) void agg64g_kernel(
    const __half* __restrict__ g, const int* __restrict__ rowptr,
    const int* __restrict__ col, const float* __restrict__ dinv,
    const float* __restrict__ bias, void* __restrict__ outv, int N) {
    __shared__ int scol[COLCAP];
    __shared__ int srp[33];
    const int tid = threadIdx.x;
    const int lane = tid & 63, wave = tid >> 6;
    const int oct = lane >> 3, sub = lane & 7;
    const int r0 = blockIdx.x * 32;
    const int lr = wave * 8 + oct;
    const int r = r0 + lr;

    if (tid < 33) {
        int rr = r0 + tid;
        srp[tid] = rowptr[rr > N ? N : rr];
    }
    __syncthreads();
    const int eBase = srp[0], eEnd = srp[32];
    const int cnt = eEnd - eBase;
    const bool staged = (cnt <= COLCAP);
    if (staged) {
        for (int i = tid; i < cnt; i += THREADS) scol[i] = col[eBase + i];
    }
    __syncthreads();

    const uint4* __restrict__ g4 = (const uint4*)g + sub;  // 8 uint4 per row
    const bool valid = (r < N);
    int start = srp[lr], end = srp[lr + 1];

    float acc[8] = {0.f, 0.f, 0.f, 0.f, 0.f, 0.f, 0.f, 0.f};
    if (valid) add8(acc, g4[(size_t)r * 8]);  // self-loop

    int e = start;
#define GLOOP64(GETC)                                                     \
    for (; e + 4 <= end; e += 4) {                                        \
        int c0 = GETC(e), c1 = GETC(e + 1), c2 = GETC(e + 2), c3 = GETC(e + 3); \
        uint4 u0 = g4[(size_t)c0 * 8];                                    \
        uint4 u1 = g4[(size_t)c1 * 8];                                    \
        uint4 u2 = g4[(size_t)c2 * 8];                                    \
        uint4 u3 = g4[(size_t)c3 * 8];                                    \
        add8(acc, u0); add8(acc, u1); add8(acc, u2); add8(acc, u3);       \
    }                                                                     \
    for (; e < end; ++e) add8(acc, g4[(size_t)GETC(e) * 8]);
    if (staged) {
#define CL(i) scol[(i) - eBase]
        GLOOP64(CL)
#undef CL
    } else {
#define CG(i) col[i]
        GLOOP64(CG)
#undef CG
    }
#undef GLOOP64

    if (valid) {
        const float dr = dinv[r];
        float res[8];
#pragma unroll
        for (int k = 0; k < 8; ++k) res[k] = acc[k] * dr;
        if constexpr (ACT) {
            const float* bp = bias + sub * 8;
#pragma unroll
            for (int k = 0; k < 8; ++k) res[k] = celu1(res[k] + bp[k]);
        }
        if constexpr (OUTH) {
            __half2 hp[4] = {__floats2half2_rn(res[0], res[1]), __floats2half2_rn(res[2], res[3]),
                             __floats2half2_rn(res[4], res[5]), __floats2half2_rn(res[6], res[7])};
            *(uint4*)((__half*)outv + (size_t)r * 64 + sub * 8) = *(uint4*)hp;
        } else {
            // final layer: out never re-read -> nt stores keep table in L2
            float* o = (float*)outv + (size_t)r * 64 + sub * 8;
            floatx4 o0 = {res[0], res[1], res[2], res[3]};
            floatx4 o1 = {res[4], res[5], res[6], res[7]};
            __builtin_nontemporal_store(o0, (floatx4*)o);
            __builtin_nontemporal_store(o1, (floatx4*)o + 1);
        }
    }
}

// ---- Aggregation F=128, two half-feature passes, LDS-staged col -----------
// 8-lane oct per (row, half): pass working set 12.8 MB (vs 25.6) for L2.
// blockIdx >= NB selects the upper feature half.

__global__ __launch_bounds__(THREADS) void agg128g_kernel(
    const __half* __restrict__ g, const int* __restrict__ rowptr,
    const int* __restrict__ col, const float* __restrict__ dinv,
    __half* __restrict__ out, int N, int NB) {
    __shared__ int scol[COLCAP];
    __shared__ int srp[33];
    const int tid = threadIdx.x;
    const int lane = tid & 63, wave = tid >> 6;
    const int oct = lane >> 3, sub = lane & 7;
    int bx = blockIdx.x;
    int half = 0;
    if (bx >= NB) { half = 1; bx -= NB; }
    const int r0 = bx * 32;
    const int lr = wave * 8 + oct;
    const int r = r0 + lr;

    if (tid < 33) {
        int rr = r0 + tid;
        srp[tid] = rowptr[rr > N ? N : rr];
    }
    __syncthreads();
    const int eBase = srp[0], eEnd = srp[32];
    const int cnt = eEnd - eBase;
    const bool staged = (cnt <= COLCAP);
    if (staged) {
        for (int i = tid; i < cnt; i += THREADS) scol[i] = col[eBase + i];
    }
    __syncthreads();

    // pre-offset by feature half + sub; row stride = 16 uint4 (128 halves)
    const uint4* __restrict__ g4 = (const uint4*)g + half * 8 + sub;
    const bool valid = (r < N);
    int start = srp[lr], end = srp[lr + 1];

    float acc[8] = {0.f, 0.f, 0.f, 0.f, 0.f, 0.f, 0.f, 0.f};
    if (valid) add8(acc, g4[(size_t)r * 16]);  // self-loop

    int e = start;
#define GLOOP128(GETC)                                                    \
    for (; e + 4 <= end; e += 4) {                                        \
        int c0 = GETC(e), c1 = GETC(e + 1), c2 = GETC(e + 2), c3 = GETC(e + 3); \
        uint4 u0 = g4[(size_t)c0 * 16];                                   \
        uint4 u1 = g4[(size_t)c1 * 16];                                   \
        uint4 u2 = g4[(size_t)c2 * 16];                                   \
        uint4 u3 = g4[(size_t)c3 * 16];                                   \
        add8(acc, u0); add8(acc, u1); add8(acc, u2); add8(acc, u3);       \
    }                                                                     \
    for (; e < end; ++e) add8(acc, g4[(size_t)GETC(e) * 16]);
    if (staged) {
#define CL(i) scol[(i) - eBase]
        GLOOP128(CL)
#undef CL
    } else {
#define CG(i) col[i]
        GLOOP128(CG)
#undef CG
    }
#undef GLOOP128

    if (valid) {
        const float dr = dinv[r];
        __half2 hp[4] = {__floats2half2_rn(acc[0] * dr, acc[1] * dr),
                         __floats2half2_rn(acc[2] * dr, acc[3] * dr),
                         __floats2half2_rn(acc[4] * dr, acc[5] * dr),
                         __floats2half2_rn(acc[6] * dr, acc[7] * dr)};
        *(uint4*)(out + (size_t)r * 128 + half * 64 + sub * 8) = *(uint4*)hp;
    }
}

// ---- MFMA dense transform: out[N,F] = [dinv*] act(X @ W + b) --------------

template <int K, int F, bool ACT, bool SCALE>
__global__ __launch_bounds__(THREADS) void mfma_gemm_kernel(
    const __half* __restrict__ X, const __half* __restrict__ Wt,
    const float* __restrict__ bias, const float* __restrict__ dinv,
    __half* __restrict__ outh, int N) {
    constexpr int KP = K + 8;  // padded LDS row stride (halves)
    constexpr int NT = F / 16;
    __shared__ __half Ws[F * KP];

    const int tid = threadIdx.x;
    for (int i = tid; i < F * K / 8; i += THREADS) {
        int f = i / (K / 8), kg = i % (K / 8);
        *(uint4*)&Ws[f * KP + kg * 8] = ((const uint4*)Wt)[i];
    }
    __syncthreads();

    const int wave = tid >> 6, lane = tid & 63;
    const int q = lane >> 4, mn = lane & 15;
    const int row0w = blockIdx.x * 64 + wave * 16;
    int arow = row0w + mn;
    if (arow >= N) arow = N - 1;  // clamp loads; garbage rows masked on store

    floatx4 acc[NT];
#pragma unroll
    for (int t = 0; t < NT; ++t) acc[t] = {0.f, 0.f, 0.f, 0.f};

    const __half* xp = X + (size_t)arow * K + q * 8;
#pragma unroll
    for (int k0 = 0; k0 < K; k0 += 32) {
        half8 a = *(const half8*)(xp + k0);
#pragma unroll
        for (int t = 0; t < NT; ++t) {
            half8 b = *(const half8*)&Ws[(t * 16 + mn) * KP + k0 + q * 8];
            acc[t] = __builtin_amdgcn_mfma_f32_16x16x32_f16(a, b, acc[t], 0, 0, 0);
        }
    }

    // D: reg i <-> row = row0w + q*4 + i, col = t*16 + mn
    const int orow0 = row0w + q * 4;
    float dv[4] = {1.f, 1.f, 1.f, 1.f};
    if constexpr (SCALE) {
#pragma unroll
        for (int i = 0; i < 4; ++i) {
            int r = orow0 + i;
            if (r < N) dv[i] = dinv[r];
        }
    }
#pragma unroll
    for (int t = 0; t < NT; ++t) {
        const int coln = t * 16 + mn;
        float bv = 0.f;
        if constexpr (ACT) bv = bias[coln];
#pragma unroll
        for (int i = 0; i < 4; ++i) {
            int r = orow0 + i;
            if (r < N) {
                float v = acc[t][i];
                if constexpr (ACT) v = celu1(v + bv);
                if constexpr (SCALE) v *= dv[i];
                outh[(size_t)r * F + coln] = __float2half(v);
            }
        }
    }
}

// ---------------------------------------------------------------------------

extern "C" void kernel_launch(void* const* d_in, const int* in_sizes, int n_in,
                              void* d_out, int out_size, void* d_ws, size_t ws_size,
                              hipStream_t stream) {
    const float* x  = (const float*)d_in[0];
    const int*   ei = (const int*)d_in[1];
    const float* W1 = (const float*)d_in[2];
    const float* b1 = (const float*)d_in[3];
    const float* W2 = (const float*)d_in[4];
    const float* b2 = (const float*)d_in[5];
    const float* W3 = (const float*)d_in[6];
    const float* b3 = (const float*)d_in[7];
    float* out = (float*)d_out;

    const int N = in_sizes[0] / 64;   // 100000
    const int E = in_sizes[1] / 2;    // 1600000
    const int* src = ei;
    const int* dst = ei + E;
    const int NBUCK = (N + BNODES - 1) >> BSHIFT;  // 391

    char* p = (char*)d_ws;
    auto carve = [&](size_t bytes) {
        void* q = p;
        p += (bytes + 255) & ~(size_t)255;
        return q;
    };
    int*    rowptr    = (int*)carve((size_t)(N + 1) * sizeof(int));
    int*    col       = (int*)carve((size_t)E * sizeof(int));
    float*  dinv      = (float*)carve((size_t)N * sizeof(float));
    int*    bucketCnt = (int*)carve(NBUCK_MAX * sizeof(int));
    int*    bucketOff = (int*)carve((NBUCK_MAX + 1) * sizeof(int));
    int*    bucketCur = (int*)carve(NBUCK_MAX * sizeof(int));
    __half* xg        = (__half*)carve((size_t)N * 64 * sizeof(__half));
    __half* Wt1       = (__half*)carve(64 * 128 * sizeof(__half));
    __half* Wt2       = (__half*)carve(128 * 128 * sizeof(__half));
    __half* Wt3       = (__half*)carve(128 * 64 * sizeof(__half));
    __half* FA        = (__half*)carve((size_t)N * 128 * sizeof(__half));
    __half* FB        = (__half*)carve((size_t)N * 128 * sizeof(__half));
    int*    ePack     = (int*)FB;  // 6.4MB; consumed by build_kernel before gemm1 writes FB

    const int AB64  = (N + 31) / 32;
    const int AB128 = (N + 31) / 32;  // 32 rows/block per half-pass
    const int GBM = (N + 63) / 64;
    const int SB = (E + CHUNK - 1) / CHUNK;
    const int n8 = N * 8;
    const int PB = (n8 + THREADS - 1) / THREADS + 128;  // f2h blocks + 128 w2h blocks

    // --- CSR build, then fused precision prep (needs dinv) ---
    hipMemsetAsync(bucketCnt, 0, NBUCK_MAX * sizeof(int), stream);
    bucket_hist_kernel<<<256, THREADS, 0, stream>>>(dst, bucketCnt, E, NBUCK);
    bucket_scan_kernel<<<1, SCANT, 0, stream>>>(bucketCnt, bucketOff, bucketCur, rowptr, NBUCK, N);
    bucket_scatter_kernel<<<SB, THREADS, 0, stream>>>(src, dst, bucketCur, ePack, E, NBUCK);
    build_kernel<<<NBUCK, THREADS, 0, stream>>>(ePack, bucketOff, rowptr, dinv, col, N);
    prep_kernel<<<PB, THREADS, 0, stream>>>(x, dinv, xg, W1, Wt1, W2, Wt2, W3, Wt3, n8);

    // --- Layer 1: s1 = Agg(x);  g1 = dinv*celu(s1@W1+b1)  (pre-scaled) ---
    agg64g_kernel<false, true><<<AB64, THREADS, 0, stream>>>(xg, rowptr, col, dinv, nullptr, FA, N);
    mfma_gemm_kernel<64, 128, true, true><<<GBM, THREADS, 0, stream>>>(FA, Wt1, b1, dinv, FB, N);

    // --- Layer 2: s2 = Agg(g1) (two half-feature passes);  a2 = celu(s2@W2+b2) ---
    agg128g_kernel<<<2 * AB128, THREADS, 0, stream>>>(FB, rowptr, col, dinv, FA, N, AB128);
    mfma_gemm_kernel<128, 128, true, false><<<GBM, THREADS, 0, stream>>>(FA, Wt2, b2, dinv, FB, N);

    // --- Layer 3: g3 = dinv*(a2@W3); out = celu(dinv*(g3[r]+sum g3)+b3) ---
    mfma_gemm_kernel<128, 64, false, true><<<GBM, THREADS, 0, stream>>>(FB, Wt3, nullptr, dinv, FA, N);
    agg64g_kernel<true, false><<<AB64, THREADS, 0, stream>>>(FA, rowptr, col, dinv, b3, out, N);
}